// Round 18
// baseline (12161.889 us; speedup 1.0000x reference)
//
#include <hip/hip_runtime.h>
#include <cstdint>
#include <cstddef>

// ---------------------------------------------------------------------------
// LSTMModel: B=128, T=256(->255 diffs), F=6, H=512, L=4, S=32, D=3
// R18 = R17 + counted-wait hygiene (no sync-semantics change):
//  - dead wpre path removed; W issued at body top (vlow check from register),
//    W latency overlaps own-poll detect (drained by poll's vmcnt(0))
//  - vlow refresh + publish(t-1) + liveness(t) issued IN-BODY as newest ops
//    (~1us runway before tail vmcnt(0)); tail stores only the fast sc0 flag
//  - counted waits audited for wave0 (+pub+live) vs others (over-retire ok)
// ---------------------------------------------------------------------------

typedef __bf16 bf16x8  __attribute__((ext_vector_type(8)));
typedef float  f32x4   __attribute__((ext_vector_type(4)));
typedef float  f32x16  __attribute__((ext_vector_type(16)));
typedef unsigned int u32x4 __attribute__((ext_vector_type(4)));
typedef unsigned int u32x2 __attribute__((ext_vector_type(2)));

// stg geometry (elements)
#define STG_SLOT  262144ull     // 4l * 2mg * 32cg * 64item * 16j
#define STG_L     65536ull
#define STG_MG    32768ull
#define STG_CG    1024ull

// ring geometry (elements): [l][mg][slot&7][cg][item][16j]
#define RING_SLOT 32768ull
#define RING_MG   (8ull*RING_SLOT)
#define RING_L    (2ull*RING_MG)
#define SZ_RING   (4ull*RING_L*2ull)                // 4 MB

// ws byte offsets
#define OFF_STG  0ull
#define SZ_STG   (257ull*STG_SLOT*2ull)
#define OFF_D    (OFF_STG + SZ_STG)
#define SZ_D     524288ull
#define OFF_BIAS (OFF_D + SZ_D)
#define SZ_BIAS  32768ull
#define OFF_FLAG (OFF_BIAS + SZ_BIAS)               // slow flags (padded)
#define SZ_FLAG  32768ull
#define OFF_FFLAG (OFF_FLAG + SZ_FLAG)              // fast flags (padded)
#define SZ_FFLAG 32768ull
#define OFF_RING (OFF_FFLAG + SZ_FFLAG)
#define OFF_BP   (OFF_RING + SZ_RING)
#define NK16_L0  33
#define BPE_L0   (64ull*NK16_L0*64ull*8ull)         // 1081344
#define BPE_STR  (64ull*64ull*64ull*8ull)           // 2097152

#define LDS_ZPAD   72
#define LDS_ZBYTES 18432
#define LDS_WBYTES 131072
#define LDS_TOTAL  (LDS_ZBYTES + LDS_WBYTES)        // 149504

#define VMWAIT(N) do { asm volatile("s_waitcnt vmcnt(" #N ")" ::: "memory"); \
                       __builtin_amdgcn_sched_barrier(0); } while (0)

__device__ __forceinline__ void gld16(u32x4& d, const unsigned short* p) {
    asm volatile("global_load_dwordx4 %0, %1, off" : "=v"(d) : "v"(p));
}
__device__ __forceinline__ void gld16_sc0(u32x4& d, const unsigned short* p) {
    asm volatile("global_load_dwordx4 %0, %1, off sc0" : "=v"(d) : "v"(p));
}
__device__ __forceinline__ int ld_fast(const int* p) {     // sc0: L1-bypass, L2 read
    int v;
    asm volatile("global_load_dword %0, %1, off sc0\n\t"
                 "s_waitcnt vmcnt(0)" : "=v"(v) : "v"(p) : "memory");
    return v;
}
__device__ __forceinline__ int ld_slow(const int* p) {
    return __hip_atomic_load(p, __ATOMIC_RELAXED, __HIP_MEMORY_SCOPE_AGENT);
}
__device__ __forceinline__ void ld_slow_async(int& v, const int* p) { // no wait
    asm volatile("global_load_dword %0, %1, off sc0 sc1" : "=v"(v) : "v"(p));
}
__device__ __forceinline__ void st_fast(int* p, int v) {   // XCD-L2 write-through
    asm volatile("global_store_dword %0, %1, off sc0" :: "v"(p), "v"(v) : "memory");
}
__device__ __forceinline__ void st_slow(int* p, int v) {   // L3/HBM write-through
    asm volatile("global_store_dword %0, %1, off sc0 sc1" :: "v"(p), "v"(v) : "memory");
}
__device__ __forceinline__ void st_cross8(void* p, unsigned long long v) {
    u32x2 d = __builtin_bit_cast(u32x2, v);
    asm volatile("global_store_dwordx2 %0, %1, off sc0 sc1" :: "v"(p), "v"(d) : "memory");
}

__device__ __forceinline__ unsigned short f2bf(float f) {
    unsigned int u = __builtin_bit_cast(unsigned int, f);
    unsigned int lsb = (u >> 16) & 1u;
    u += 0x7fffu + lsb;
    return (unsigned short)(u >> 16);
}
__device__ __forceinline__ float bf2f(unsigned short s) {
    unsigned int u = ((unsigned int)s) << 16;
    return __builtin_bit_cast(float, u);
}
__device__ __forceinline__ float fsig(float x)  { return 1.0f / (1.0f + __expf(-x)); }
__device__ __forceinline__ float ftanh(float x) { float e = __expf(2.0f * x); return 1.0f - 2.0f / (e + 1.0f); }

// ---------------------------------------------------------------------------
__global__ void prep_bias(const float* __restrict__ b, float* __restrict__ bias_ws) {
    int idx = blockIdx.x * 256 + threadIdx.x;
    if (idx >= 4 * 2048) return;
    int l = idx >> 11, c = idx & 2047;
    int j = ((c >> 6) << 4) + (c & 15);
    int gate = (c >> 4) & 3;
    bias_ws[idx] = b[l * 2048 + gate * 512 + j];
}

// ---------------------------------------------------------------------------
__global__ void prep_bp32(int layer, int NK16,
                          const float* __restrict__ W0, const float* __restrict__ Wk,
                          const float* __restrict__ U, unsigned short* __restrict__ bp) {
    int idx = blockIdx.x * 256 + threadIdx.x;
    int total = 64 * NK16 * 64;
    if (idx >= total) return;
    int lane = idx & 63;
    int rest = idx >> 6;
    int ks = rest % NK16;
    int ct = rest / NK16;
    int c = ct * 32 + (lane & 31);
    int j = ((c >> 6) << 4) + (c & 15);
    int gate = (c >> 4) & 3;
    int sc = gate * 512 + j;
    int kbase = ks * 16 + ((lane >> 5) << 3);
    unsigned short outv[8];
#pragma unroll
    for (int i = 0; i < 8; i++) {
        int k = kbase + i;
        float v = 0.0f;
        if (layer == 0) {
            if (k < 8) { if (k < 6) v = W0[(size_t)k * 2048 + sc]; }
            else if (k < 520) v = U[(size_t)(k - 8) * 2048 + sc];
        } else {
            if (k < 512) v = Wk[((size_t)(layer - 1) * 512 + k) * 2048 + sc];
            else         v = U[((size_t)layer * 512 + (k - 512)) * 2048 + sc];
        }
        outv[i] = f2bf(v);
    }
    *(uint4*)(bp + (size_t)idx * 8) = *(const uint4*)outv;
}

// ---------------------------------------------------------------------------
__global__ void diffk(const float* __restrict__ x, const float* __restrict__ bound,
                      unsigned short* __restrict__ dbuf) {
    int idx = blockIdx.x * 256 + threadIdx.x;
    if (idx >= 255 * 128) return;
    int item = idx & 127, t = idx >> 7;
    const float* xr = x + ((size_t)item * 256 + t) * 6;
    unsigned short row[8];
#pragma unroll
    for (int f = 0; f < 6; f++) row[f] = f2bf((xr[6 + f] - xr[f]) / bound[f]);
    row[6] = 0; row[7] = 0;
    *(uint4*)(dbuf + (size_t)idx * 8) = *(const uint4*)row;
}

// ---------------------------------------------------------------------------
// Persistent LSTM: block -> stage = blk&7 (layer=stage>>1, mg=stage&1), cg=blk>>3
// Flags (padded x32 ints): fastf[fid*32] own fast ("t+1" = step t done, sc0);
// slowf[fid*32] publish ("slot p acked&visible" when >= p; stored IN-BODY of
// step p+1); slowf[fid*32+1] liveness ("t" = step t-1 done, in-body).
// stg slot s holds h of step s-1 (written in body of step s; slot 255 post-loop).
// ---------------------------------------------------------------------------
__global__ __launch_bounds__(256, 1) void lstm_persist(
    const unsigned short* __restrict__ dbuf,
    unsigned short* __restrict__ stg,
    unsigned short* __restrict__ ring,
    const unsigned short* __restrict__ bp_all,
    const float* __restrict__ bias,
    int* __restrict__ slowf,
    int* __restrict__ fastf)
{
    extern __shared__ char smem[];
    float* zsm = (float*)smem;
    unsigned short* wsm = (unsigned short*)(smem + LDS_ZBYTES);

    // ---- entry acquire: purge stale (poison/replay) L1/L2 lines ONCE -----
    (void)__hip_atomic_load(&slowf[0], __ATOMIC_ACQUIRE, __HIP_MEMORY_SCOPE_AGENT);

    const int blk   = blockIdx.x;
    const int stage = blk & 7;
    const int layer = stage >> 1;
    const int mg    = stage & 1;
    const int cg    = blk >> 3;
    const int tid   = threadIdx.x;
    const int w     = tid >> 6;
    const int lane  = tid & 63;
    const int NK16  = (layer == 0) ? NK16_L0 : 64;

    // ---- stage this block's weight tile into LDS (once) ------------------
    {
        const unsigned short* src = bp_all
            + (layer == 0 ? 0ull : (BPE_L0 + (size_t)(layer - 1) * BPE_STR))
            + (size_t)(cg * 2) * NK16 * 64 * 8;
        int nv = 2 * NK16 * 64;
        for (int e = tid; e < nv; e += 256)
            ((uint4*)wsm)[e] = ((const uint4*)src)[e];
    }
    __syncthreads();

    // ---- per-wave constants ----------------------------------------------
    const int mt    = w >> 1;
    const int ntl   = w & 1;
    const int khalf = lane >> 5;
    const int arow  = mg * 64 + mt * 32 + (lane & 31);
    const int aloc  = arow & 63;
    const unsigned short* wbase = wsm + (size_t)ntl * NK16 * 512 + (size_t)lane * 8;
    const int citem = tid >> 2;
    const int jsub  = (tid & 3) << 2;
    const f32x4 bI = *(const f32x4*)(bias + layer * 2048 + cg * 64 + 0  + jsub);
    const f32x4 bF = *(const f32x4*)(bias + layer * 2048 + cg * 64 + 16 + jsub);
    const f32x4 bG = *(const f32x4*)(bias + layer * 2048 + cg * 64 + 32 + jsub);
    const f32x4 bO = *(const f32x4*)(bias + layer * 2048 + cg * 64 + 48 + jsub);

    const int own_base = stage * 32;
    const int lo_base  = (stage - 2) * 32;          // lower layer, same mg
    const int myfp     = (own_base + cg) * 32;
    const int pf       = lane & 31;
    const int ownfp    = (own_base + pf) * 32;
    const int lofp     = (lo_base + pf) * 32;

    unsigned short* ringW = ring + (size_t)layer * RING_L + (size_t)mg * RING_MG;
    const unsigned short* ringR = ringW;

    f32x4 creg = (f32x4){0.f, 0.f, 0.f, 0.f};
    u32x4 A0[16], A1[16];
    unsigned long long hpack_prev = 0ull;

    int vlow = 0x7fffffff;
    if (layer > 0 && lane < 32) { ld_slow_async(vlow, &slowf[lofp]); }
    VMWAIT(0);

    for (int t = 0; t < 255; t++) {
        f32x16 c0 = {0.f,0.f,0.f,0.f,0.f,0.f,0.f,0.f,0.f,0.f,0.f,0.f,0.f,0.f,0.f,0.f};
        f32x16 c1 = c0, c2 = c0, c3 = c0;

        auto consume = [&](u32x4 (&buf)[16], int wc0) {
#pragma unroll
            for (int j = 0; j < 16; j++) {
                int ch = wc0 + j;
                bf16x8 av = __builtin_bit_cast(bf16x8, buf[j]);
                bf16x8 bv = *(const bf16x8*)(wbase + (size_t)ch * 512);
                f32x16& cc = ((ch & 3) == 0) ? c0 : ((ch & 3) == 1) ? c1
                           : ((ch & 3) == 2) ? c2 : c3;
                cc = __builtin_amdgcn_mfma_f32_32x32x16_bf16(av, bv, cc, 0, 0, 0);
            }
        };

        auto own_poll = [&]() {     // first vmcnt(0) drains in-flight W loads
            for (;;) {              // (issued just above) => overlap with detect
                int v = (lane < 32) ? ld_fast(&fastf[ownfp]) : 0x7fffffff;
                if (__all(v >= t)) break;
                if (lane < 32) { int v2 = ld_slow(&slowf[ownfp + 1]); v = v > v2 ? v : v2; }
                if (__all(v >= t)) break;
                __builtin_amdgcn_s_sleep(1);
            }
            __builtin_amdgcn_sched_barrier(0);
        };

        const unsigned short* rU = ringR + (size_t)(t & 7) * RING_SLOT
                                 + (size_t)aloc * 16 + (size_t)khalf * 8;
        // in-body cross store target: slot t holds h of step t-1
        unsigned short* crossp = stg + (size_t)t * STG_SLOT
            + (size_t)layer * STG_L + (size_t)mg * STG_MG
            + (size_t)cg * STG_CG + (size_t)citem * 16 + jsub;

        if (layer == 0) {
            own_poll();
            const unsigned short* pD = dbuf + ((size_t)t * 128 + arow) * 8;
            auto issue0 = [&](u32x4 (&buf)[16], int kc0) {
#pragma unroll
                for (int j = 0; j < 16; j++) {
                    int kc = kc0 + j;
                    if (kc == 0 && khalf == 0) { gld16(buf[j], pD); }
                    else {
                        int hk = (kc * 16 + khalf * 8 - 8) & 511;
                        gld16_sc0(buf[j], ringR + (size_t)(t & 7) * RING_SLOT
                                  + (size_t)(hk >> 4) * STG_CG + (size_t)aloc * 16 + (hk & 15));
                    }
                }
            };
            u32x4 ax;
            issue0(A0, 0); issue0(A1, 16);
            {   int hk = (32 * 16 + khalf * 8 - 8) & 511;
                gld16_sc0(ax, ringR + (size_t)(t & 7) * RING_SLOT
                          + (size_t)(hk >> 4) * STG_CG + (size_t)aloc * 16 + (hk & 15)); }
            st_cross8(crossp, hpack_prev);           // 34 outstanding (others)
            if (tid == 0 && t > 0) {                 // wave0: +2 => 36
                st_slow(&slowf[myfp], t - 1);        // publish: slot t-1 acked
                st_slow(&slowf[myfp + 1], t);        // liveness: step t-1 done
            }
            VMWAIT(18); consume(A0, 0);              // A0 retired (both cases)
            VMWAIT(2);  consume(A1, 16);             // A1 retired
            VMWAIT(1);                               // ax retired (w0: +pub/live gone too)
            {   bf16x8 av = __builtin_bit_cast(bf16x8, ax);
                bf16x8 bv = *(const bf16x8*)(wbase + (size_t)32 * 512);
                c0 = __builtin_amdgcn_mfma_f32_32x32x16_bf16(av, bv, c0, 0, 0, 0); }
        } else {
            // ---- lower check from REGISTER (retired long ago); spin rare -
            for (;;) {
                int v = (lane < 32) ? vlow : 0x7fffffff;
                if (__all(v >= t + 1)) break;
                __builtin_amdgcn_s_sleep(1);
                if (lane < 32) ld_slow_async(vlow, &slowf[lofp]);
                VMWAIT(0);
            }
            __builtin_amdgcn_sched_barrier(0);
            // ---- W issue (slot t+1 = lower h(t)); latency overlaps poll --
            const unsigned short* aW = stg + (size_t)(t + 1) * STG_SLOT
                + (size_t)(layer - 1) * STG_L + (size_t)mg * STG_MG
                + (size_t)aloc * 16 + (size_t)khalf * 8;
#pragma unroll
            for (int j = 0; j < 16; j++) gld16(A0[j], aW + (size_t)j * STG_CG);
#pragma unroll
            for (int j = 0; j < 16; j++) gld16(A1[j], aW + (size_t)(16 + j) * STG_CG);
            // ---- own poll: its vmcnt(0) drains W during sibling wait -----
            own_poll();
            consume(A0, 0);                                   // W chunks 0-15
            consume(A1, 16);                                  // W chunks 16-31
            // ---- U issue + cross + vlow refresh + pub/live (newest) ------
#pragma unroll
            for (int j = 0; j < 16; j++) gld16_sc0(A0[j], rU + (size_t)j * STG_CG);
#pragma unroll
            for (int j = 0; j < 16; j++) gld16_sc0(A1[j], rU + (size_t)(16 + j) * STG_CG);
            st_cross8(crossp, hpack_prev);                    // 33
            if (lane < 32) ld_slow_async(vlow, &slowf[lofp]); // 34 (wave-level)
            if (tid == 0 && t > 0) {                          // wave0: 36
                st_slow(&slowf[myfp], t - 1);                 // publish
                st_slow(&slowf[myfp + 1], t);                 // liveness
            }
            VMWAIT(18); consume(A0, 32);      // U0-15 retired (w0 over-retires ok)
            VMWAIT(2);  consume(A1, 48);      // all U retired
        }

        f32x16 acc = (c0 + c1) + (c2 + c3);

        // ---- z -> LDS exchange ------------------------------------------
        {
            const int col   = ntl * 32 + (lane & 31);
            const int rbase = mt * 32 + 4 * khalf;
#pragma unroll
            for (int r = 0; r < 16; r++) {
                int row = rbase + (r & 3) + 8 * (r >> 2);
                zsm[row * LDS_ZPAD + col] = acc[r];
            }
        }
        if (layer == 0) {
            __syncthreads();
        } else {
            asm volatile("s_waitcnt lgkmcnt(0)" ::: "memory");
            __builtin_amdgcn_s_barrier();
            asm volatile("" ::: "memory");
            __builtin_amdgcn_sched_barrier(0);
        }

        // ---- cell update ------------------------------------------------
        unsigned long long hpack;
        {
            const float* zr = zsm + citem * LDS_ZPAD + jsub;
            f32x4 zi = *(const f32x4*)(zr + 0);
            f32x4 zf = *(const f32x4*)(zr + 16);
            f32x4 zg = *(const f32x4*)(zr + 32);
            f32x4 zo = *(const f32x4*)(zr + 48);
            unsigned short hq[4];
#pragma unroll
            for (int q = 0; q < 4; q++) {
                float i_ = fsig(zi[q] + bI[q]);
                float f_ = fsig(zf[q] + bF[q]);
                float g_ = ftanh(zg[q] + bG[q]);
                float o_ = fsig(zo[q] + bO[q]);
                float cn = f_ * creg[q] + i_ * g_;
                creg[q] = cn;
                hq[q] = f2bf(o_ * ftanh(cn));
            }
            __builtin_memcpy(&hpack, hq, 8);
        }
        hpack_prev = hpack;

        // ---- ring store + tail drain (ring L2; cross/vlow long-issued) ---
        *(unsigned long long*)(ringW + (size_t)((t + 1) & 7) * RING_SLOT
            + (size_t)cg * STG_CG + (size_t)citem * 16 + jsub) = hpack;
        if (layer == 0) {
            __syncthreads();
        } else {
            asm volatile("s_waitcnt vmcnt(0)" ::: "memory");
            __builtin_amdgcn_s_barrier();
            asm volatile("" ::: "memory");
            __builtin_amdgcn_sched_barrier(0);
        }
        // ---- release: fast flag ONLY (sc0, cheap ack) --------------------
        if (tid == 0) st_fast(&fastf[myfp], t + 1);
    }

    // ---- post-loop: cross-store slot 255 (h of step 254), publish --------
    {
        unsigned short* crossp = stg + 255ull * STG_SLOT
            + (size_t)layer * STG_L + (size_t)mg * STG_MG
            + (size_t)cg * STG_CG + (size_t)citem * 16 + jsub;
        st_cross8(crossp, hpack_prev);
    }
    asm volatile("s_waitcnt vmcnt(0)" ::: "memory");
    __syncthreads();
    if (tid == 0) {
        st_slow(&slowf[myfp], 255);          // all slots visible
        st_slow(&slowf[myfp + 1], 256);      // liveness final
    }
}

// ---------------------------------------------------------------------------
__global__ void headk(const unsigned short* __restrict__ stg,
                      const float* __restrict__ Wd, const float* __restrict__ bd,
                      const float* __restrict__ bound, const float* __restrict__ centre,
                      float* __restrict__ out) {
    (void)__hip_atomic_load((const int*)stg, __ATOMIC_ACQUIRE, __HIP_MEMORY_SCOPE_AGENT);
    int idx = blockIdx.x * 256 + threadIdx.x;
    if (idx >= 12288) return;
    int dd = idx % 3;
    int rest = idx / 3;
    int sdx = rest & 31;
    int b = rest >> 5;
    size_t base = (size_t)(224 + sdx) * STG_SLOT + 3ull * STG_L
                + (size_t)(b >> 6) * STG_MG + (size_t)(b & 63) * 16;
    float acc = 0.0f;
    for (int jj = 0; jj < 512; jj++) {
        unsigned short hv = stg[base + (size_t)(jj >> 4) * STG_CG + (jj & 15)];
        acc += bf2f(hv) * Wd[jj * 3 + dd];
    }
    float o = acc + bd[dd];
    out[idx] = o;
    out[12288 + idx] = o * bound[dd] + centre[dd];
}

// ---------------------------------------------------------------------------
extern "C" void kernel_launch(void* const* d_in, const int* in_sizes, int n_in,
                              void* d_out, int out_size, void* d_ws, size_t ws_size,
                              hipStream_t stream) {
    const float* x      = (const float*)d_in[0];
    const float* centre = (const float*)d_in[1];
    const float* bound  = (const float*)d_in[2];
    const float* W0     = (const float*)d_in[3];
    const float* Wk     = (const float*)d_in[4];
    const float* U      = (const float*)d_in[5];
    const float* b      = (const float*)d_in[6];
    const float* Wd     = (const float*)d_in[7];
    const float* bd     = (const float*)d_in[8];

    char* ws = (char*)d_ws;
    unsigned short* stg     = (unsigned short*)(ws + OFF_STG);
    unsigned short* dbuf    = (unsigned short*)(ws + OFF_D);
    float*          bias_ws = (float*)(ws + OFF_BIAS);
    int*            slowf   = (int*)(ws + OFF_FLAG);
    int*            fastf   = (int*)(ws + OFF_FFLAG);
    unsigned short* ring    = (unsigned short*)(ws + OFF_RING);
    unsigned short* bp      = (unsigned short*)(ws + OFF_BP);

    (void)hipMemsetAsync(slowf, 0, SZ_FLAG + SZ_FFLAG + SZ_RING, stream);

    prep_bias<<<32, 256, 0, stream>>>(b, bias_ws);
    prep_bp32<<<528, 256, 0, stream>>>(0, NK16_L0, W0, Wk, U, bp);
    for (int l = 1; l < 4; l++)
        prep_bp32<<<1024, 256, 0, stream>>>(l, 64, W0, Wk, U,
                                            bp + BPE_L0 + (size_t)(l - 1) * BPE_STR);
    diffk<<<128, 256, 0, stream>>>(x, bound, dbuf);

    (void)hipFuncSetAttribute((const void*)lstm_persist,
                              hipFuncAttributeMaxDynamicSharedMemorySize, LDS_TOTAL);
    lstm_persist<<<256, 256, LDS_TOTAL, stream>>>(dbuf, stg, ring, bp, bias_ws,
                                                  slowf, fastf);

    headk<<<48, 256, 0, stream>>>(stg, Wd, bd, bound, centre, (float*)d_out);
}

// Round 19
// 1460.108 us; speedup vs baseline: 8.3294x; 8.3294x over previous
//
#include <hip/hip_runtime.h>
#include <cstdint>
#include <cstddef>

// ---------------------------------------------------------------------------
// LSTMModel: B=128, T=256(->255 diffs), F=6, H=512, L=4, S=32, D=3
// R19 = R17 (passing, 1354us; tail flag semantics UNCHANGED) + reorder:
//  - W issued SPECULATIVELY at step top; validated by register vlow sampled
//    at prior tail (publish happened-before sample => data correct);
//    fallback spin + reload retained for shortfall
//  - own_poll's vmcnt(0) now drains W + tail pub/live + vlow in ONE overlap
//    with sibling detect (removes 2 serial VMWAIT(0)s from the cycle)
// ---------------------------------------------------------------------------

typedef __bf16 bf16x8  __attribute__((ext_vector_type(8)));
typedef float  f32x4   __attribute__((ext_vector_type(4)));
typedef float  f32x16  __attribute__((ext_vector_type(16)));
typedef unsigned int u32x4 __attribute__((ext_vector_type(4)));
typedef unsigned int u32x2 __attribute__((ext_vector_type(2)));

// stg geometry (elements)
#define STG_SLOT  262144ull     // 4l * 2mg * 32cg * 64item * 16j
#define STG_L     65536ull
#define STG_MG    32768ull
#define STG_CG    1024ull

// ring geometry (elements): [l][mg][slot&7][cg][item][16j]
#define RING_SLOT 32768ull
#define RING_MG   (8ull*RING_SLOT)
#define RING_L    (2ull*RING_MG)
#define SZ_RING   (4ull*RING_L*2ull)                // 4 MB

// ws byte offsets
#define OFF_STG  0ull
#define SZ_STG   (257ull*STG_SLOT*2ull)
#define OFF_D    (OFF_STG + SZ_STG)
#define SZ_D     524288ull
#define OFF_BIAS (OFF_D + SZ_D)
#define SZ_BIAS  32768ull
#define OFF_FLAG (OFF_BIAS + SZ_BIAS)               // slow flags (padded)
#define SZ_FLAG  32768ull
#define OFF_FFLAG (OFF_FLAG + SZ_FLAG)              // fast flags (padded)
#define SZ_FFLAG 32768ull
#define OFF_RING (OFF_FFLAG + SZ_FFLAG)
#define OFF_BP   (OFF_RING + SZ_RING)
#define NK16_L0  33
#define BPE_L0   (64ull*NK16_L0*64ull*8ull)         // 1081344
#define BPE_STR  (64ull*64ull*64ull*8ull)           // 2097152

#define LDS_ZPAD   72
#define LDS_ZBYTES 18432
#define LDS_WBYTES 131072
#define LDS_TOTAL  (LDS_ZBYTES + LDS_WBYTES)        // 149504

#define VMWAIT(N) do { asm volatile("s_waitcnt vmcnt(" #N ")" ::: "memory"); \
                       __builtin_amdgcn_sched_barrier(0); } while (0)

__device__ __forceinline__ void gld16(u32x4& d, const unsigned short* p) {
    asm volatile("global_load_dwordx4 %0, %1, off" : "=v"(d) : "v"(p));
}
__device__ __forceinline__ void gld16_sc0(u32x4& d, const unsigned short* p) {
    asm volatile("global_load_dwordx4 %0, %1, off sc0" : "=v"(d) : "v"(p));
}
__device__ __forceinline__ int ld_fast(const int* p) {     // sc0: L1-bypass, L2 read
    int v;
    asm volatile("global_load_dword %0, %1, off sc0\n\t"
                 "s_waitcnt vmcnt(0)" : "=v"(v) : "v"(p) : "memory");
    return v;
}
__device__ __forceinline__ int ld_slow(const int* p) {
    return __hip_atomic_load(p, __ATOMIC_RELAXED, __HIP_MEMORY_SCOPE_AGENT);
}
__device__ __forceinline__ void ld_slow_async(int& v, const int* p) { // no wait
    asm volatile("global_load_dword %0, %1, off sc0 sc1" : "=v"(v) : "v"(p));
}
__device__ __forceinline__ void st_cross8(void* p, unsigned long long v) {
    u32x2 d = __builtin_bit_cast(u32x2, v);
    asm volatile("global_store_dwordx2 %0, %1, off sc0 sc1" :: "v"(p), "v"(d) : "memory");
}

__device__ __forceinline__ unsigned short f2bf(float f) {
    unsigned int u = __builtin_bit_cast(unsigned int, f);
    unsigned int lsb = (u >> 16) & 1u;
    u += 0x7fffu + lsb;
    return (unsigned short)(u >> 16);
}
__device__ __forceinline__ float bf2f(unsigned short s) {
    unsigned int u = ((unsigned int)s) << 16;
    return __builtin_bit_cast(float, u);
}
__device__ __forceinline__ float fsig(float x)  { return 1.0f / (1.0f + __expf(-x)); }
__device__ __forceinline__ float ftanh(float x) { float e = __expf(2.0f * x); return 1.0f - 2.0f / (e + 1.0f); }

// ---------------------------------------------------------------------------
__global__ void prep_bias(const float* __restrict__ b, float* __restrict__ bias_ws) {
    int idx = blockIdx.x * 256 + threadIdx.x;
    if (idx >= 4 * 2048) return;
    int l = idx >> 11, c = idx & 2047;
    int j = ((c >> 6) << 4) + (c & 15);
    int gate = (c >> 4) & 3;
    bias_ws[idx] = b[l * 2048 + gate * 512 + j];
}

// ---------------------------------------------------------------------------
__global__ void prep_bp32(int layer, int NK16,
                          const float* __restrict__ W0, const float* __restrict__ Wk,
                          const float* __restrict__ U, unsigned short* __restrict__ bp) {
    int idx = blockIdx.x * 256 + threadIdx.x;
    int total = 64 * NK16 * 64;
    if (idx >= total) return;
    int lane = idx & 63;
    int rest = idx >> 6;
    int ks = rest % NK16;
    int ct = rest / NK16;
    int c = ct * 32 + (lane & 31);
    int j = ((c >> 6) << 4) + (c & 15);
    int gate = (c >> 4) & 3;
    int sc = gate * 512 + j;
    int kbase = ks * 16 + ((lane >> 5) << 3);
    unsigned short outv[8];
#pragma unroll
    for (int i = 0; i < 8; i++) {
        int k = kbase + i;
        float v = 0.0f;
        if (layer == 0) {
            if (k < 8) { if (k < 6) v = W0[(size_t)k * 2048 + sc]; }
            else if (k < 520) v = U[(size_t)(k - 8) * 2048 + sc];
        } else {
            if (k < 512) v = Wk[((size_t)(layer - 1) * 512 + k) * 2048 + sc];
            else         v = U[((size_t)layer * 512 + (k - 512)) * 2048 + sc];
        }
        outv[i] = f2bf(v);
    }
    *(uint4*)(bp + (size_t)idx * 8) = *(const uint4*)outv;
}

// ---------------------------------------------------------------------------
__global__ void diffk(const float* __restrict__ x, const float* __restrict__ bound,
                      unsigned short* __restrict__ dbuf) {
    int idx = blockIdx.x * 256 + threadIdx.x;
    if (idx >= 255 * 128) return;
    int item = idx & 127, t = idx >> 7;
    const float* xr = x + ((size_t)item * 256 + t) * 6;
    unsigned short row[8];
#pragma unroll
    for (int f = 0; f < 6; f++) row[f] = f2bf((xr[6 + f] - xr[f]) / bound[f]);
    row[6] = 0; row[7] = 0;
    *(uint4*)(dbuf + (size_t)idx * 8) = *(const uint4*)row;
}

// ---------------------------------------------------------------------------
// Persistent LSTM: block -> stage = blk&7 (layer=stage>>1, mg=stage&1), cg=blk>>3
// Flags (padded x32 ints): fastf[fid*32] own fast ("t+1" = step t done, sc0);
// slowf[fid*32] publish ("slot p visible" when >= p, stored at TAIL of step p);
// slowf[fid*32+1] liveness ("t+1" = step t done, stored at TAIL of step t).
// stg slot s holds h of step s-1 (written in body of step s; slot 255 post-loop).
// ---------------------------------------------------------------------------
__global__ __launch_bounds__(256, 1) void lstm_persist(
    const unsigned short* __restrict__ dbuf,
    unsigned short* __restrict__ stg,
    unsigned short* __restrict__ ring,
    const unsigned short* __restrict__ bp_all,
    const float* __restrict__ bias,
    int* __restrict__ slowf,
    int* __restrict__ fastf)
{
    extern __shared__ char smem[];
    float* zsm = (float*)smem;
    unsigned short* wsm = (unsigned short*)(smem + LDS_ZBYTES);

    // ---- entry acquire: purge stale (poison/replay) L1/L2 lines ONCE -----
    (void)__hip_atomic_load(&slowf[0], __ATOMIC_ACQUIRE, __HIP_MEMORY_SCOPE_AGENT);

    const int blk   = blockIdx.x;
    const int stage = blk & 7;
    const int layer = stage >> 1;
    const int mg    = stage & 1;
    const int cg    = blk >> 3;
    const int tid   = threadIdx.x;
    const int w     = tid >> 6;
    const int lane  = tid & 63;
    const int NK16  = (layer == 0) ? NK16_L0 : 64;

    // ---- stage this block's weight tile into LDS (once) ------------------
    {
        const unsigned short* src = bp_all
            + (layer == 0 ? 0ull : (BPE_L0 + (size_t)(layer - 1) * BPE_STR))
            + (size_t)(cg * 2) * NK16 * 64 * 8;
        int nv = 2 * NK16 * 64;
        for (int e = tid; e < nv; e += 256)
            ((uint4*)wsm)[e] = ((const uint4*)src)[e];
    }
    __syncthreads();

    // ---- per-wave constants ----------------------------------------------
    const int mt    = w >> 1;
    const int ntl   = w & 1;
    const int khalf = lane >> 5;
    const int arow  = mg * 64 + mt * 32 + (lane & 31);
    const int aloc  = arow & 63;
    const unsigned short* wbase = wsm + (size_t)ntl * NK16 * 512 + (size_t)lane * 8;
    const int citem = tid >> 2;
    const int jsub  = (tid & 3) << 2;
    const f32x4 bI = *(const f32x4*)(bias + layer * 2048 + cg * 64 + 0  + jsub);
    const f32x4 bF = *(const f32x4*)(bias + layer * 2048 + cg * 64 + 16 + jsub);
    const f32x4 bG = *(const f32x4*)(bias + layer * 2048 + cg * 64 + 32 + jsub);
    const f32x4 bO = *(const f32x4*)(bias + layer * 2048 + cg * 64 + 48 + jsub);

    const int own_base = stage * 32;
    const int lo_base  = (stage - 2) * 32;          // lower layer, same mg
    const int myfp     = (own_base + cg) * 32;
    const int pf       = lane & 31;
    const int ownfp    = (own_base + pf) * 32;
    const int lofp     = (lo_base + pf) * 32;

    unsigned short* ringW = ring + (size_t)layer * RING_L + (size_t)mg * RING_MG;
    const unsigned short* ringR = ringW;

    f32x4 creg = (f32x4){0.f, 0.f, 0.f, 0.f};
    u32x4 A0[16], A1[16];
    unsigned long long hpack_prev = 0ull;

    int vlow = 0;                   // register copy; 0 = nothing published yet
    if (layer > 0 && lane < 32) { ld_slow_async(vlow, &slowf[lofp]); }
    VMWAIT(0);

    for (int t = 0; t < 255; t++) {
        f32x16 c0 = {0.f,0.f,0.f,0.f,0.f,0.f,0.f,0.f,0.f,0.f,0.f,0.f,0.f,0.f,0.f,0.f};
        f32x16 c1 = c0, c2 = c0, c3 = c0;

        auto consume = [&](u32x4 (&buf)[16], int wc0) {
#pragma unroll
            for (int j = 0; j < 16; j++) {
                int ch = wc0 + j;
                bf16x8 av = __builtin_bit_cast(bf16x8, buf[j]);
                bf16x8 bv = *(const bf16x8*)(wbase + (size_t)ch * 512);
                f32x16& cc = ((ch & 3) == 0) ? c0 : ((ch & 3) == 1) ? c1
                           : ((ch & 3) == 2) ? c2 : c3;
                cc = __builtin_amdgcn_mfma_f32_32x32x16_bf16(av, bv, cc, 0, 0, 0);
            }
        };

        auto own_poll = [&]() {     // ld_fast vmcnt(0) drains W + tail stores +
            for (;;) {              // vlow, overlapped with sibling detect
                int v = (lane < 32) ? ld_fast(&fastf[ownfp]) : 0x7fffffff;
                if (__all(v >= t)) break;
                if (lane < 32) { int v2 = ld_slow(&slowf[ownfp + 1]); v = v > v2 ? v : v2; }
                if (__all(v >= t)) break;
                __builtin_amdgcn_s_sleep(1);
            }
            __builtin_amdgcn_sched_barrier(0);
        };

        const unsigned short* rU = ringR + (size_t)(t & 7) * RING_SLOT
                                 + (size_t)aloc * 16 + (size_t)khalf * 8;
        // in-body cross store target: slot t holds h of step t-1
        unsigned short* crossp = stg + (size_t)t * STG_SLOT
            + (size_t)layer * STG_L + (size_t)mg * STG_MG
            + (size_t)cg * STG_CG + (size_t)citem * 16 + jsub;

        if (layer == 0) {
            own_poll();
            const unsigned short* pD = dbuf + ((size_t)t * 128 + arow) * 8;
            auto issue0 = [&](u32x4 (&buf)[16], int kc0) {
#pragma unroll
                for (int j = 0; j < 16; j++) {
                    int kc = kc0 + j;
                    if (kc == 0 && khalf == 0) { gld16(buf[j], pD); }
                    else {
                        int hk = (kc * 16 + khalf * 8 - 8) & 511;
                        gld16_sc0(buf[j], ringR + (size_t)(t & 7) * RING_SLOT
                                  + (size_t)(hk >> 4) * STG_CG + (size_t)aloc * 16 + (hk & 15));
                    }
                }
            };
            u32x4 ax;
            issue0(A0, 0); issue0(A1, 16);
            {   int hk = (32 * 16 + khalf * 8 - 8) & 511;
                gld16_sc0(ax, ringR + (size_t)(t & 7) * RING_SLOT
                          + (size_t)(hk >> 4) * STG_CG + (size_t)aloc * 16 + (hk & 15)); }
            st_cross8(crossp, hpack_prev);           // 34 outstanding
            VMWAIT(18); consume(A0, 0);
            VMWAIT(2);  consume(A1, 16);
            VMWAIT(1);
            {   bf16x8 av = __builtin_bit_cast(bf16x8, ax);
                bf16x8 bv = *(const bf16x8*)(wbase + (size_t)32 * 512);
                c0 = __builtin_amdgcn_mfma_f32_32x32x16_bf16(av, bv, c0, 0, 0, 0); }
        } else {
            // ---- speculative W issue (slot t+1) at step top --------------
            const unsigned short* aW = stg + (size_t)(t + 1) * STG_SLOT
                + (size_t)(layer - 1) * STG_L + (size_t)mg * STG_MG
                + (size_t)aloc * 16 + (size_t)khalf * 8;
#pragma unroll
            for (int j = 0; j < 16; j++) gld16(A0[j], aW + (size_t)j * STG_CG);
#pragma unroll
            for (int j = 0; j < 16; j++) gld16(A1[j], aW + (size_t)(16 + j) * STG_CG);
            // ---- own poll: vmcnt(0) drains W + tail stores + vlow --------
            own_poll();
            // ---- validate speculation with register vlow (retired) -------
            {
                int v = (lane < 32) ? vlow : 0x7fffffff;
                if (!__all(v >= t + 1)) {
                    // fallback: spin for publish, then re-issue W
                    for (;;) {
                        v = (lane < 32) ? vlow : 0x7fffffff;
                        if (__all(v >= t + 1)) break;
                        __builtin_amdgcn_s_sleep(1);
                        if (lane < 32) ld_slow_async(vlow, &slowf[lofp]);
                        VMWAIT(0);
                    }
                    __builtin_amdgcn_sched_barrier(0);
#pragma unroll
                    for (int j = 0; j < 16; j++) gld16(A0[j], aW + (size_t)j * STG_CG);
#pragma unroll
                    for (int j = 0; j < 16; j++) gld16(A1[j], aW + (size_t)(16 + j) * STG_CG);
                    VMWAIT(0);
                }
            }
            __builtin_amdgcn_sched_barrier(0);
            consume(A0, 0);                                   // W chunks 0-15
            consume(A1, 16);                                  // W chunks 16-31
            // ---- U issue (ring, XCD-L2) + cross store as newest op -------
#pragma unroll
            for (int j = 0; j < 16; j++) gld16_sc0(A0[j], rU + (size_t)j * STG_CG);
#pragma unroll
            for (int j = 0; j < 16; j++) gld16_sc0(A1[j], rU + (size_t)(16 + j) * STG_CG);
            st_cross8(crossp, hpack_prev);           // 33 outstanding
            VMWAIT(17); consume(A0, 32);             // U0-15 retired
            VMWAIT(1);  consume(A1, 48);             // all U retired (cross out)
        }

        f32x16 acc = (c0 + c1) + (c2 + c3);

        // ---- z -> LDS exchange ------------------------------------------
        {
            const int col   = ntl * 32 + (lane & 31);
            const int rbase = mt * 32 + 4 * khalf;
#pragma unroll
            for (int r = 0; r < 16; r++) {
                int row = rbase + (r & 3) + 8 * (r >> 2);
                zsm[row * LDS_ZPAD + col] = acc[r];
            }
        }
        if (layer == 0) {
            __syncthreads();
        } else {
            asm volatile("s_waitcnt lgkmcnt(0)" ::: "memory");
            __builtin_amdgcn_s_barrier();
            asm volatile("" ::: "memory");
            __builtin_amdgcn_sched_barrier(0);
        }

        // ---- cell update ------------------------------------------------
        unsigned long long hpack;
        {
            const float* zr = zsm + citem * LDS_ZPAD + jsub;
            f32x4 zi = *(const f32x4*)(zr + 0);
            f32x4 zf = *(const f32x4*)(zr + 16);
            f32x4 zg = *(const f32x4*)(zr + 32);
            f32x4 zo = *(const f32x4*)(zr + 48);
            unsigned short hq[4];
#pragma unroll
            for (int q = 0; q < 4; q++) {
                float i_ = fsig(zi[q] + bI[q]);
                float f_ = fsig(zf[q] + bF[q]);
                float g_ = ftanh(zg[q] + bG[q]);
                float o_ = fsig(zo[q] + bO[q]);
                float cn = f_ * creg[q] + i_ * g_;
                creg[q] = cn;
                hq[q] = f2bf(o_ * ftanh(cn));
            }
            __builtin_memcpy(&hpack, hq, 8);
        }
        hpack_prev = hpack;

        // ---- ring store + tail drain (ring L2 + in-body cross) -----------
        *(unsigned long long*)(ringW + (size_t)((t + 1) & 7) * RING_SLOT
            + (size_t)cg * STG_CG + (size_t)citem * 16 + jsub) = hpack;
        if (layer == 0) {
            __syncthreads();
        } else {
            asm volatile("s_waitcnt vmcnt(0)" ::: "memory");
            __builtin_amdgcn_s_barrier();
            asm volatile("" ::: "memory");
            __builtin_amdgcn_sched_barrier(0);
        }
        // ---- releases (EXACT R17): fast, liveness(t+1), publish(t) -------
        if (tid == 0) {
            int nv = t + 1;
            asm volatile("global_store_dword %0, %1, off sc0"
                         :: "v"(&fastf[myfp]), "v"(nv) : "memory");
            __hip_atomic_store(&slowf[myfp + 1], nv, __ATOMIC_RELAXED,
                               __HIP_MEMORY_SCOPE_AGENT);   // liveness
            __hip_atomic_store(&slowf[myfp], t, __ATOMIC_RELAXED,
                               __HIP_MEMORY_SCOPE_AGENT);   // slot t visible
        }
        // ---- vlow refresh for next step (retires inside next own_poll) ---
        if (layer > 0 && lane < 32) ld_slow_async(vlow, &slowf[lofp]);
    }

    // ---- post-loop: cross-store slot 255 (h of step 254), publish --------
    {
        unsigned short* crossp = stg + 255ull * STG_SLOT
            + (size_t)layer * STG_L + (size_t)mg * STG_MG
            + (size_t)cg * STG_CG + (size_t)citem * 16 + jsub;
        st_cross8(crossp, hpack_prev);
    }
    asm volatile("s_waitcnt vmcnt(0)" ::: "memory");
    __syncthreads();
    if (tid == 0)
        __hip_atomic_store(&slowf[myfp], 255, __ATOMIC_RELAXED,
                           __HIP_MEMORY_SCOPE_AGENT);
}

// ---------------------------------------------------------------------------
__global__ void headk(const unsigned short* __restrict__ stg,
                      const float* __restrict__ Wd, const float* __restrict__ bd,
                      const float* __restrict__ bound, const float* __restrict__ centre,
                      float* __restrict__ out) {
    (void)__hip_atomic_load((const int*)stg, __ATOMIC_ACQUIRE, __HIP_MEMORY_SCOPE_AGENT);
    int idx = blockIdx.x * 256 + threadIdx.x;
    if (idx >= 12288) return;
    int dd = idx % 3;
    int rest = idx / 3;
    int sdx = rest & 31;
    int b = rest >> 5;
    size_t base = (size_t)(224 + sdx) * STG_SLOT + 3ull * STG_L
                + (size_t)(b >> 6) * STG_MG + (size_t)(b & 63) * 16;
    float acc = 0.0f;
    for (int jj = 0; jj < 512; jj++) {
        unsigned short hv = stg[base + (size_t)(jj >> 4) * STG_CG + (jj & 15)];
        acc += bf2f(hv) * Wd[jj * 3 + dd];
    }
    float o = acc + bd[dd];
    out[idx] = o;
    out[12288 + idx] = o * bound[dd] + centre[dd];
}

// ---------------------------------------------------------------------------
extern "C" void kernel_launch(void* const* d_in, const int* in_sizes, int n_in,
                              void* d_out, int out_size, void* d_ws, size_t ws_size,
                              hipStream_t stream) {
    const float* x      = (const float*)d_in[0];
    const float* centre = (const float*)d_in[1];
    const float* bound  = (const float*)d_in[2];
    const float* W0     = (const float*)d_in[3];
    const float* Wk     = (const float*)d_in[4];
    const float* U      = (const float*)d_in[5];
    const float* b      = (const float*)d_in[6];
    const float* Wd     = (const float*)d_in[7];
    const float* bd     = (const float*)d_in[8];

    char* ws = (char*)d_ws;
    unsigned short* stg     = (unsigned short*)(ws + OFF_STG);
    unsigned short* dbuf    = (unsigned short*)(ws + OFF_D);
    float*          bias_ws = (float*)(ws + OFF_BIAS);
    int*            slowf   = (int*)(ws + OFF_FLAG);
    int*            fastf   = (int*)(ws + OFF_FFLAG);
    unsigned short* ring    = (unsigned short*)(ws + OFF_RING);
    unsigned short* bp      = (unsigned short*)(ws + OFF_BP);

    (void)hipMemsetAsync(slowf, 0, SZ_FLAG + SZ_FFLAG + SZ_RING, stream);

    prep_bias<<<32, 256, 0, stream>>>(b, bias_ws);
    prep_bp32<<<528, 256, 0, stream>>>(0, NK16_L0, W0, Wk, U, bp);
    for (int l = 1; l < 4; l++)
        prep_bp32<<<1024, 256, 0, stream>>>(l, 64, W0, Wk, U,
                                            bp + BPE_L0 + (size_t)(l - 1) * BPE_STR);
    diffk<<<128, 256, 0, stream>>>(x, bound, dbuf);

    (void)hipFuncSetAttribute((const void*)lstm_persist,
                              hipFuncAttributeMaxDynamicSharedMemorySize, LDS_TOTAL);
    lstm_persist<<<256, 256, LDS_TOTAL, stream>>>(dbuf, stg, ring, bp, bias_ws,
                                                  slowf, fastf);

    headk<<<48, 256, 0, stream>>>(stg, Wd, bd, bound, centre, (float*)d_out);
}

// Round 20
// 1391.970 us; speedup vs baseline: 8.7372x; 1.0490x over previous
//
#include <hip/hip_runtime.h>
#include <cstdint>
#include <cstddef>

// ---------------------------------------------------------------------------
// LSTMModel: B=128, T=256(->255 diffs), F=6, H=512, L=4, S=32, D=3
// R20 = R17 (best passing, 1354us) + ONE change: poll loop consults the slow
// L3 liveness fallback only every 8th iteration (fast L2 path otherwise).
// Everything else byte-identical to R17.
// ---------------------------------------------------------------------------

typedef __bf16 bf16x8  __attribute__((ext_vector_type(8)));
typedef float  f32x4   __attribute__((ext_vector_type(4)));
typedef float  f32x16  __attribute__((ext_vector_type(16)));
typedef unsigned int u32x4 __attribute__((ext_vector_type(4)));
typedef unsigned int u32x2 __attribute__((ext_vector_type(2)));

// stg geometry (elements)
#define STG_SLOT  262144ull     // 4l * 2mg * 32cg * 64item * 16j
#define STG_L     65536ull
#define STG_MG    32768ull
#define STG_CG    1024ull

// ring geometry (elements): [l][mg][slot&7][cg][item][16j]
#define RING_SLOT 32768ull
#define RING_MG   (8ull*RING_SLOT)
#define RING_L    (2ull*RING_MG)
#define SZ_RING   (4ull*RING_L*2ull)                // 4 MB

// ws byte offsets
#define OFF_STG  0ull
#define SZ_STG   (257ull*STG_SLOT*2ull)
#define OFF_D    (OFF_STG + SZ_STG)
#define SZ_D     524288ull
#define OFF_BIAS (OFF_D + SZ_D)
#define SZ_BIAS  32768ull
#define OFF_FLAG (OFF_BIAS + SZ_BIAS)               // slow flags (padded)
#define SZ_FLAG  32768ull
#define OFF_FFLAG (OFF_FLAG + SZ_FLAG)              // fast flags (padded)
#define SZ_FFLAG 32768ull
#define OFF_RING (OFF_FFLAG + SZ_FFLAG)
#define OFF_BP   (OFF_RING + SZ_RING)
#define NK16_L0  33
#define BPE_L0   (64ull*NK16_L0*64ull*8ull)         // 1081344
#define BPE_STR  (64ull*64ull*64ull*8ull)           // 2097152

#define LDS_ZPAD   72
#define LDS_ZBYTES 18432
#define LDS_WBYTES 131072
#define LDS_TOTAL  (LDS_ZBYTES + LDS_WBYTES)        // 149504

#define VMWAIT(N) do { asm volatile("s_waitcnt vmcnt(" #N ")" ::: "memory"); \
                       __builtin_amdgcn_sched_barrier(0); } while (0)

__device__ __forceinline__ void gld16(u32x4& d, const unsigned short* p) {
    asm volatile("global_load_dwordx4 %0, %1, off" : "=v"(d) : "v"(p));
}
__device__ __forceinline__ void gld16_sc0(u32x4& d, const unsigned short* p) {
    asm volatile("global_load_dwordx4 %0, %1, off sc0" : "=v"(d) : "v"(p));
}
__device__ __forceinline__ int ld_fast(const int* p) {     // sc0: L1-bypass, L2 read
    int v;
    asm volatile("global_load_dword %0, %1, off sc0\n\t"
                 "s_waitcnt vmcnt(0)" : "=v"(v) : "v"(p) : "memory");
    return v;
}
__device__ __forceinline__ int ld_slow(const int* p) {
    return __hip_atomic_load(p, __ATOMIC_RELAXED, __HIP_MEMORY_SCOPE_AGENT);
}
__device__ __forceinline__ void ld_slow_async(int& v, const int* p) { // no wait
    asm volatile("global_load_dword %0, %1, off sc0 sc1" : "=v"(v) : "v"(p));
}
__device__ __forceinline__ void st_cross8(void* p, unsigned long long v) {
    u32x2 d = __builtin_bit_cast(u32x2, v);
    asm volatile("global_store_dwordx2 %0, %1, off sc0 sc1" :: "v"(p), "v"(d) : "memory");
}

__device__ __forceinline__ unsigned short f2bf(float f) {
    unsigned int u = __builtin_bit_cast(unsigned int, f);
    unsigned int lsb = (u >> 16) & 1u;
    u += 0x7fffu + lsb;
    return (unsigned short)(u >> 16);
}
__device__ __forceinline__ float bf2f(unsigned short s) {
    unsigned int u = ((unsigned int)s) << 16;
    return __builtin_bit_cast(float, u);
}
__device__ __forceinline__ float fsig(float x)  { return 1.0f / (1.0f + __expf(-x)); }
__device__ __forceinline__ float ftanh(float x) { float e = __expf(2.0f * x); return 1.0f - 2.0f / (e + 1.0f); }

// ---------------------------------------------------------------------------
__global__ void prep_bias(const float* __restrict__ b, float* __restrict__ bias_ws) {
    int idx = blockIdx.x * 256 + threadIdx.x;
    if (idx >= 4 * 2048) return;
    int l = idx >> 11, c = idx & 2047;
    int j = ((c >> 6) << 4) + (c & 15);
    int gate = (c >> 4) & 3;
    bias_ws[idx] = b[l * 2048 + gate * 512 + j];
}

// ---------------------------------------------------------------------------
__global__ void prep_bp32(int layer, int NK16,
                          const float* __restrict__ W0, const float* __restrict__ Wk,
                          const float* __restrict__ U, unsigned short* __restrict__ bp) {
    int idx = blockIdx.x * 256 + threadIdx.x;
    int total = 64 * NK16 * 64;
    if (idx >= total) return;
    int lane = idx & 63;
    int rest = idx >> 6;
    int ks = rest % NK16;
    int ct = rest / NK16;
    int c = ct * 32 + (lane & 31);
    int j = ((c >> 6) << 4) + (c & 15);
    int gate = (c >> 4) & 3;
    int sc = gate * 512 + j;
    int kbase = ks * 16 + ((lane >> 5) << 3);
    unsigned short outv[8];
#pragma unroll
    for (int i = 0; i < 8; i++) {
        int k = kbase + i;
        float v = 0.0f;
        if (layer == 0) {
            if (k < 8) { if (k < 6) v = W0[(size_t)k * 2048 + sc]; }
            else if (k < 520) v = U[(size_t)(k - 8) * 2048 + sc];
        } else {
            if (k < 512) v = Wk[((size_t)(layer - 1) * 512 + k) * 2048 + sc];
            else         v = U[((size_t)layer * 512 + (k - 512)) * 2048 + sc];
        }
        outv[i] = f2bf(v);
    }
    *(uint4*)(bp + (size_t)idx * 8) = *(const uint4*)outv;
}

// ---------------------------------------------------------------------------
__global__ void diffk(const float* __restrict__ x, const float* __restrict__ bound,
                      unsigned short* __restrict__ dbuf) {
    int idx = blockIdx.x * 256 + threadIdx.x;
    if (idx >= 255 * 128) return;
    int item = idx & 127, t = idx >> 7;
    const float* xr = x + ((size_t)item * 256 + t) * 6;
    unsigned short row[8];
#pragma unroll
    for (int f = 0; f < 6; f++) row[f] = f2bf((xr[6 + f] - xr[f]) / bound[f]);
    row[6] = 0; row[7] = 0;
    *(uint4*)(dbuf + (size_t)idx * 8) = *(const uint4*)row;
}

// ---------------------------------------------------------------------------
// Persistent LSTM: block -> stage = blk&7 (layer=stage>>1, mg=stage&1), cg=blk>>3
// Flags (padded x32 ints): fastf[fid*32] own fast ("t+1" = step t done, sc0);
// slowf[fid*32] publish ("slot p visible" when >= p, stored at TAIL of step p);
// slowf[fid*32+1] liveness ("t+1" = step t done, stored at TAIL of step t).
// stg slot s holds h of step s-1 (written in body of step s; slot 255 post-loop).
// ---------------------------------------------------------------------------
__global__ __launch_bounds__(256, 1) void lstm_persist(
    const unsigned short* __restrict__ dbuf,
    unsigned short* __restrict__ stg,
    unsigned short* __restrict__ ring,
    const unsigned short* __restrict__ bp_all,
    const float* __restrict__ bias,
    int* __restrict__ slowf,
    int* __restrict__ fastf)
{
    extern __shared__ char smem[];
    float* zsm = (float*)smem;
    unsigned short* wsm = (unsigned short*)(smem + LDS_ZBYTES);

    // ---- entry acquire: purge stale (poison/replay) L1/L2 lines ONCE -----
    (void)__hip_atomic_load(&slowf[0], __ATOMIC_ACQUIRE, __HIP_MEMORY_SCOPE_AGENT);

    const int blk   = blockIdx.x;
    const int stage = blk & 7;
    const int layer = stage >> 1;
    const int mg    = stage & 1;
    const int cg    = blk >> 3;
    const int tid   = threadIdx.x;
    const int w     = tid >> 6;
    const int lane  = tid & 63;
    const int NK16  = (layer == 0) ? NK16_L0 : 64;

    // ---- stage this block's weight tile into LDS (once) ------------------
    {
        const unsigned short* src = bp_all
            + (layer == 0 ? 0ull : (BPE_L0 + (size_t)(layer - 1) * BPE_STR))
            + (size_t)(cg * 2) * NK16 * 64 * 8;
        int nv = 2 * NK16 * 64;
        for (int e = tid; e < nv; e += 256)
            ((uint4*)wsm)[e] = ((const uint4*)src)[e];
    }
    __syncthreads();

    // ---- per-wave constants ----------------------------------------------
    const int mt    = w >> 1;
    const int ntl   = w & 1;
    const int khalf = lane >> 5;
    const int arow  = mg * 64 + mt * 32 + (lane & 31);
    const int aloc  = arow & 63;
    const unsigned short* wbase = wsm + (size_t)ntl * NK16 * 512 + (size_t)lane * 8;
    const int citem = tid >> 2;
    const int jsub  = (tid & 3) << 2;
    const f32x4 bI = *(const f32x4*)(bias + layer * 2048 + cg * 64 + 0  + jsub);
    const f32x4 bF = *(const f32x4*)(bias + layer * 2048 + cg * 64 + 16 + jsub);
    const f32x4 bG = *(const f32x4*)(bias + layer * 2048 + cg * 64 + 32 + jsub);
    const f32x4 bO = *(const f32x4*)(bias + layer * 2048 + cg * 64 + 48 + jsub);

    const int own_base = stage * 32;
    const int lo_base  = (stage - 2) * 32;          // lower layer, same mg
    const int myfp     = (own_base + cg) * 32;
    const int pf       = lane & 31;
    const int ownfp    = (own_base + pf) * 32;
    const int lofp     = (lo_base + pf) * 32;

    unsigned short* ringW = ring + (size_t)layer * RING_L + (size_t)mg * RING_MG;
    const unsigned short* ringR = ringW;

    f32x4 creg = (f32x4){0.f, 0.f, 0.f, 0.f};
    u32x4 A0[16], A1[16];
    unsigned long long hpack_prev = 0ull;
    bool wpre = false;

    int vlow = 0x7fffffff;
    if (layer > 0 && lane < 32) { ld_slow_async(vlow, &slowf[lofp]); }
    VMWAIT(0);

    for (int t = 0; t < 255; t++) {
        f32x16 c0 = {0.f,0.f,0.f,0.f,0.f,0.f,0.f,0.f,0.f,0.f,0.f,0.f,0.f,0.f,0.f,0.f};
        f32x16 c1 = c0, c2 = c0, c3 = c0;

        auto consume = [&](u32x4 (&buf)[16], int wc0) {
#pragma unroll
            for (int j = 0; j < 16; j++) {
                int ch = wc0 + j;
                bf16x8 av = __builtin_bit_cast(bf16x8, buf[j]);
                bf16x8 bv = *(const bf16x8*)(wbase + (size_t)ch * 512);
                f32x16& cc = ((ch & 3) == 0) ? c0 : ((ch & 3) == 1) ? c1
                           : ((ch & 3) == 2) ? c2 : c3;
                cc = __builtin_amdgcn_mfma_f32_32x32x16_bf16(av, bv, cc, 0, 0, 0);
            }
        };

        auto own_poll = [&]() {     // fast L2 path every iter; slow L3 liveness
            int it = 0;             // fallback only every 8th iter
            for (;;) {
                int v = (lane < 32) ? ld_fast(&fastf[ownfp]) : 0x7fffffff;
                if (__all(v >= t)) break;
                if ((++it & 7) == 0) {
                    if (lane < 32) { int v2 = ld_slow(&slowf[ownfp + 1]); v = v > v2 ? v : v2; }
                    if (__all(v >= t)) break;
                }
                __builtin_amdgcn_s_sleep(1);
            }
            __builtin_amdgcn_sched_barrier(0);
        };

        const unsigned short* rU = ringR + (size_t)(t & 7) * RING_SLOT
                                 + (size_t)aloc * 16 + (size_t)khalf * 8;
        // in-body cross store target: slot t holds h of step t-1
        unsigned short* crossp = stg + (size_t)t * STG_SLOT
            + (size_t)layer * STG_L + (size_t)mg * STG_MG
            + (size_t)cg * STG_CG + (size_t)citem * 16 + jsub;

        if (layer == 0) {
            own_poll();
            const unsigned short* pD = dbuf + ((size_t)t * 128 + arow) * 8;
            auto issue0 = [&](u32x4 (&buf)[16], int kc0) {
#pragma unroll
                for (int j = 0; j < 16; j++) {
                    int kc = kc0 + j;
                    if (kc == 0 && khalf == 0) { gld16(buf[j], pD); }
                    else {
                        int hk = (kc * 16 + khalf * 8 - 8) & 511;
                        gld16_sc0(buf[j], ringR + (size_t)(t & 7) * RING_SLOT
                                  + (size_t)(hk >> 4) * STG_CG + (size_t)aloc * 16 + (hk & 15));
                    }
                }
            };
            u32x4 ax;
            issue0(A0, 0); issue0(A1, 16);
            {   int hk = (32 * 16 + khalf * 8 - 8) & 511;
                gld16_sc0(ax, ringR + (size_t)(t & 7) * RING_SLOT
                          + (size_t)(hk >> 4) * STG_CG + (size_t)aloc * 16 + (hk & 15)); }
            st_cross8(crossp, hpack_prev);           // newest op [34 outstanding]
            VMWAIT(18); consume(A0, 0);              // A0 retired
            VMWAIT(2);  consume(A1, 16);             // A1 retired (ax,cross remain)
            VMWAIT(1);                               // ax retired (cross remains)
            {   bf16x8 av = __builtin_bit_cast(bf16x8, ax);
                bf16x8 bv = *(const bf16x8*)(wbase + (size_t)32 * 512);
                c0 = __builtin_amdgcn_mfma_f32_32x32x16_bf16(av, bv, c0, 0, 0, 0); }
        } else {
            // ---- in-body W fallback (startup / lower not far enough) -----
            if (!wpre) {
                VMWAIT(0);
                for (;;) {
                    int v = (lane < 32) ? vlow : 0x7fffffff;
                    if (__all(v >= t + 1)) break;
                    __builtin_amdgcn_s_sleep(1);
                    if (lane < 32) ld_slow_async(vlow, &slowf[lofp]);
                    VMWAIT(0);
                }
                __builtin_amdgcn_sched_barrier(0);
                const unsigned short* aW = stg + (size_t)(t + 1) * STG_SLOT
                    + (size_t)(layer - 1) * STG_L + (size_t)mg * STG_MG
                    + (size_t)aloc * 16 + (size_t)khalf * 8;
#pragma unroll
                for (int j = 0; j < 16; j++) gld16(A0[j], aW + (size_t)j * STG_CG);
#pragma unroll
                for (int j = 0; j < 16; j++) gld16(A1[j], aW + (size_t)(16 + j) * STG_CG);
            }
            // ---- own poll: single vmcnt(0) drains W + vlow ---------------
            own_poll();
            consume(A0, 0);                                   // W chunks 0-15
            consume(A1, 16);                                  // W chunks 16-31
            // ---- U phase (ring, XCD-L2) + cross store as newest op -------
#pragma unroll
            for (int j = 0; j < 16; j++) gld16_sc0(A0[j], rU + (size_t)j * STG_CG);
#pragma unroll
            for (int j = 0; j < 16; j++) gld16_sc0(A1[j], rU + (size_t)(16 + j) * STG_CG);
            st_cross8(crossp, hpack_prev);           // newest op [33 outstanding]
            VMWAIT(17); consume(A0, 32);             // U0-15 retired
            VMWAIT(1);  consume(A1, 48);             // all U retired (cross remains)
        }

        f32x16 acc = (c0 + c1) + (c2 + c3);

        // ---- z -> LDS exchange ------------------------------------------
        {
            const int col   = ntl * 32 + (lane & 31);
            const int rbase = mt * 32 + 4 * khalf;
#pragma unroll
            for (int r = 0; r < 16; r++) {
                int row = rbase + (r & 3) + 8 * (r >> 2);
                zsm[row * LDS_ZPAD + col] = acc[r];
            }
        }
        if (layer == 0) {
            __syncthreads();
        } else {
            asm volatile("s_waitcnt lgkmcnt(0)" ::: "memory");
            __builtin_amdgcn_s_barrier();
            asm volatile("" ::: "memory");
            __builtin_amdgcn_sched_barrier(0);
        }

        // ---- cell update ------------------------------------------------
        unsigned long long hpack;
        {
            const float* zr = zsm + citem * LDS_ZPAD + jsub;
            f32x4 zi = *(const f32x4*)(zr + 0);
            f32x4 zf = *(const f32x4*)(zr + 16);
            f32x4 zg = *(const f32x4*)(zr + 32);
            f32x4 zo = *(const f32x4*)(zr + 48);
            unsigned short hq[4];
#pragma unroll
            for (int q = 0; q < 4; q++) {
                float i_ = fsig(zi[q] + bI[q]);
                float f_ = fsig(zf[q] + bF[q]);
                float g_ = ftanh(zg[q] + bG[q]);
                float o_ = fsig(zo[q] + bO[q]);
                float cn = f_ * creg[q] + i_ * g_;
                creg[q] = cn;
                hq[q] = f2bf(o_ * ftanh(cn));
            }
            __builtin_memcpy(&hpack, hq, 8);
        }
        hpack_prev = hpack;

        // ---- ring store + tail drain (ring L2 + in-body cross) -----------
        *(unsigned long long*)(ringW + (size_t)((t + 1) & 7) * RING_SLOT
            + (size_t)cg * STG_CG + (size_t)citem * 16 + jsub) = hpack;
        if (layer == 0) {
            __syncthreads();
        } else {
            asm volatile("s_waitcnt vmcnt(0)" ::: "memory");
            __builtin_amdgcn_s_barrier();
            asm volatile("" ::: "memory");
            __builtin_amdgcn_sched_barrier(0);
        }
        // ---- releases: fast flag, liveness(t+1), publish(t) --------------
        if (tid == 0) {
            int nv = t + 1;
            asm volatile("global_store_dword %0, %1, off sc0"
                         :: "v"(&fastf[myfp]), "v"(nv) : "memory");
            __hip_atomic_store(&slowf[myfp + 1], nv, __ATOMIC_RELAXED,
                               __HIP_MEMORY_SCOPE_AGENT);   // liveness
            __hip_atomic_store(&slowf[myfp], t, __ATOMIC_RELAXED,
                               __HIP_MEMORY_SCOPE_AGENT);   // slot t visible
        }

        // ---- opportunistic W prefetch for step t+1 (slot t+2) ------------
        wpre = false;
        if (layer > 0) {
            if (t < 254) {
                int v = (lane < 32) ? vlow : 0x7fffffff;
                if (__all(v >= t + 2)) {
                    const unsigned short* aW2 = stg + (size_t)(t + 2) * STG_SLOT
                        + (size_t)(layer - 1) * STG_L + (size_t)mg * STG_MG
                        + (size_t)aloc * 16 + (size_t)khalf * 8;
#pragma unroll
                    for (int j = 0; j < 16; j++) gld16(A0[j], aW2 + (size_t)j * STG_CG);
#pragma unroll
                    for (int j = 0; j < 16; j++) gld16(A1[j], aW2 + (size_t)(16 + j) * STG_CG);
                    wpre = true;
                }
            }
            if (lane < 32) ld_slow_async(vlow, &slowf[lofp]);  // drained at next poll
        }
    }

    // ---- post-loop: cross-store slot 255 (h of step 254), publish 255 ----
    {
        unsigned short* crossp = stg + 255ull * STG_SLOT
            + (size_t)layer * STG_L + (size_t)mg * STG_MG
            + (size_t)cg * STG_CG + (size_t)citem * 16 + jsub;
        st_cross8(crossp, hpack_prev);
    }
    asm volatile("s_waitcnt vmcnt(0)" ::: "memory");
    __syncthreads();
    if (tid == 0)
        __hip_atomic_store(&slowf[myfp], 255, __ATOMIC_RELAXED,
                           __HIP_MEMORY_SCOPE_AGENT);
}

// ---------------------------------------------------------------------------
__global__ void headk(const unsigned short* __restrict__ stg,
                      const float* __restrict__ Wd, const float* __restrict__ bd,
                      const float* __restrict__ bound, const float* __restrict__ centre,
                      float* __restrict__ out) {
    (void)__hip_atomic_load((const int*)stg, __ATOMIC_ACQUIRE, __HIP_MEMORY_SCOPE_AGENT);
    int idx = blockIdx.x * 256 + threadIdx.x;
    if (idx >= 12288) return;
    int dd = idx % 3;
    int rest = idx / 3;
    int sdx = rest & 31;
    int b = rest >> 5;
    size_t base = (size_t)(224 + sdx) * STG_SLOT + 3ull * STG_L
                + (size_t)(b >> 6) * STG_MG + (size_t)(b & 63) * 16;
    float acc = 0.0f;
    for (int jj = 0; jj < 512; jj++) {
        unsigned short hv = stg[base + (size_t)(jj >> 4) * STG_CG + (jj & 15)];
        acc += bf2f(hv) * Wd[jj * 3 + dd];
    }
    float o = acc + bd[dd];
    out[idx] = o;
    out[12288 + idx] = o * bound[dd] + centre[dd];
}

// ---------------------------------------------------------------------------
extern "C" void kernel_launch(void* const* d_in, const int* in_sizes, int n_in,
                              void* d_out, int out_size, void* d_ws, size_t ws_size,
                              hipStream_t stream) {
    const float* x      = (const float*)d_in[0];
    const float* centre = (const float*)d_in[1];
    const float* bound  = (const float*)d_in[2];
    const float* W0     = (const float*)d_in[3];
    const float* Wk     = (const float*)d_in[4];
    const float* U      = (const float*)d_in[5];
    const float* b      = (const float*)d_in[6];
    const float* Wd     = (const float*)d_in[7];
    const float* bd     = (const float*)d_in[8];

    char* ws = (char*)d_ws;
    unsigned short* stg     = (unsigned short*)(ws + OFF_STG);
    unsigned short* dbuf    = (unsigned short*)(ws + OFF_D);
    float*          bias_ws = (float*)(ws + OFF_BIAS);
    int*            slowf   = (int*)(ws + OFF_FLAG);
    int*            fastf   = (int*)(ws + OFF_FFLAG);
    unsigned short* ring    = (unsigned short*)(ws + OFF_RING);
    unsigned short* bp      = (unsigned short*)(ws + OFF_BP);

    (void)hipMemsetAsync(slowf, 0, SZ_FLAG + SZ_FFLAG + SZ_RING, stream);

    prep_bias<<<32, 256, 0, stream>>>(b, bias_ws);
    prep_bp32<<<528, 256, 0, stream>>>(0, NK16_L0, W0, Wk, U, bp);
    for (int l = 1; l < 4; l++)
        prep_bp32<<<1024, 256, 0, stream>>>(l, 64, W0, Wk, U,
                                            bp + BPE_L0 + (size_t)(l - 1) * BPE_STR);
    diffk<<<128, 256, 0, stream>>>(x, bound, dbuf);

    (void)hipFuncSetAttribute((const void*)lstm_persist,
                              hipFuncAttributeMaxDynamicSharedMemorySize, LDS_TOTAL);
    lstm_persist<<<256, 256, LDS_TOTAL, stream>>>(dbuf, stg, ring, bp, bias_ws,
                                                  slowf, fastf);

    headk<<<48, 256, 0, stream>>>(stg, Wd, bd, bound, centre, (float*)d_out);
}

// Round 21
// 1353.380 us; speedup vs baseline: 8.9863x; 1.0285x over previous
//
#include <hip/hip_runtime.h>
#include <cstdint>
#include <cstddef>

// ---------------------------------------------------------------------------
// LSTMModel: B=128, T=256(->255 diffs), F=6, H=512, L=4, S=32, D=3
// FINAL = R17 (best passing, 1354us). Persistent stage->XCD pipeline:
//  - weights LDS-resident (MFMA 32x32x16 fragment-native layout)
//  - own-stage h via XCD-L2 ring (plain stores, sc0 reads)
//  - cross-stage h via write-through stg, lagged publish
//  - dual flags: fast sc0 (XCD-local) + slow agent L3 (liveness/publish)
//  - in-body cross store as newest vmem op; counted waits keep slow acks
//    off the serial cycle
// Structural floor: 255 sequential inter-block handoffs (~3-4us each through
// the coherence point) + ~1.1us body; see session notes.
// ---------------------------------------------------------------------------

typedef __bf16 bf16x8  __attribute__((ext_vector_type(8)));
typedef float  f32x4   __attribute__((ext_vector_type(4)));
typedef float  f32x16  __attribute__((ext_vector_type(16)));
typedef unsigned int u32x4 __attribute__((ext_vector_type(4)));
typedef unsigned int u32x2 __attribute__((ext_vector_type(2)));

// stg geometry (elements)
#define STG_SLOT  262144ull     // 4l * 2mg * 32cg * 64item * 16j
#define STG_L     65536ull
#define STG_MG    32768ull
#define STG_CG    1024ull

// ring geometry (elements): [l][mg][slot&7][cg][item][16j]
#define RING_SLOT 32768ull
#define RING_MG   (8ull*RING_SLOT)
#define RING_L    (2ull*RING_MG)
#define SZ_RING   (4ull*RING_L*2ull)                // 4 MB

// ws byte offsets
#define OFF_STG  0ull
#define SZ_STG   (257ull*STG_SLOT*2ull)
#define OFF_D    (OFF_STG + SZ_STG)
#define SZ_D     524288ull
#define OFF_BIAS (OFF_D + SZ_D)
#define SZ_BIAS  32768ull
#define OFF_FLAG (OFF_BIAS + SZ_BIAS)               // slow flags (padded)
#define SZ_FLAG  32768ull
#define OFF_FFLAG (OFF_FLAG + SZ_FLAG)              // fast flags (padded)
#define SZ_FFLAG 32768ull
#define OFF_RING (OFF_FFLAG + SZ_FFLAG)
#define OFF_BP   (OFF_RING + SZ_RING)
#define NK16_L0  33
#define BPE_L0   (64ull*NK16_L0*64ull*8ull)         // 1081344
#define BPE_STR  (64ull*64ull*64ull*8ull)           // 2097152

#define LDS_ZPAD   72
#define LDS_ZBYTES 18432
#define LDS_WBYTES 131072
#define LDS_TOTAL  (LDS_ZBYTES + LDS_WBYTES)        // 149504

#define VMWAIT(N) do { asm volatile("s_waitcnt vmcnt(" #N ")" ::: "memory"); \
                       __builtin_amdgcn_sched_barrier(0); } while (0)

__device__ __forceinline__ void gld16(u32x4& d, const unsigned short* p) {
    asm volatile("global_load_dwordx4 %0, %1, off" : "=v"(d) : "v"(p));
}
__device__ __forceinline__ void gld16_sc0(u32x4& d, const unsigned short* p) {
    asm volatile("global_load_dwordx4 %0, %1, off sc0" : "=v"(d) : "v"(p));
}
__device__ __forceinline__ int ld_fast(const int* p) {     // sc0: L1-bypass, L2 read
    int v;
    asm volatile("global_load_dword %0, %1, off sc0\n\t"
                 "s_waitcnt vmcnt(0)" : "=v"(v) : "v"(p) : "memory");
    return v;
}
__device__ __forceinline__ int ld_slow(const int* p) {
    return __hip_atomic_load(p, __ATOMIC_RELAXED, __HIP_MEMORY_SCOPE_AGENT);
}
__device__ __forceinline__ void ld_slow_async(int& v, const int* p) { // no wait
    asm volatile("global_load_dword %0, %1, off sc0 sc1" : "=v"(v) : "v"(p));
}
__device__ __forceinline__ void st_cross8(void* p, unsigned long long v) {
    u32x2 d = __builtin_bit_cast(u32x2, v);
    asm volatile("global_store_dwordx2 %0, %1, off sc0 sc1" :: "v"(p), "v"(d) : "memory");
}

__device__ __forceinline__ unsigned short f2bf(float f) {
    unsigned int u = __builtin_bit_cast(unsigned int, f);
    unsigned int lsb = (u >> 16) & 1u;
    u += 0x7fffu + lsb;
    return (unsigned short)(u >> 16);
}
__device__ __forceinline__ float bf2f(unsigned short s) {
    unsigned int u = ((unsigned int)s) << 16;
    return __builtin_bit_cast(float, u);
}
__device__ __forceinline__ float fsig(float x)  { return 1.0f / (1.0f + __expf(-x)); }
__device__ __forceinline__ float ftanh(float x) { float e = __expf(2.0f * x); return 1.0f - 2.0f / (e + 1.0f); }

// ---------------------------------------------------------------------------
__global__ void prep_bias(const float* __restrict__ b, float* __restrict__ bias_ws) {
    int idx = blockIdx.x * 256 + threadIdx.x;
    if (idx >= 4 * 2048) return;
    int l = idx >> 11, c = idx & 2047;
    int j = ((c >> 6) << 4) + (c & 15);
    int gate = (c >> 4) & 3;
    bias_ws[idx] = b[l * 2048 + gate * 512 + j];
}

// ---------------------------------------------------------------------------
__global__ void prep_bp32(int layer, int NK16,
                          const float* __restrict__ W0, const float* __restrict__ Wk,
                          const float* __restrict__ U, unsigned short* __restrict__ bp) {
    int idx = blockIdx.x * 256 + threadIdx.x;
    int total = 64 * NK16 * 64;
    if (idx >= total) return;
    int lane = idx & 63;
    int rest = idx >> 6;
    int ks = rest % NK16;
    int ct = rest / NK16;
    int c = ct * 32 + (lane & 31);
    int j = ((c >> 6) << 4) + (c & 15);
    int gate = (c >> 4) & 3;
    int sc = gate * 512 + j;
    int kbase = ks * 16 + ((lane >> 5) << 3);
    unsigned short outv[8];
#pragma unroll
    for (int i = 0; i < 8; i++) {
        int k = kbase + i;
        float v = 0.0f;
        if (layer == 0) {
            if (k < 8) { if (k < 6) v = W0[(size_t)k * 2048 + sc]; }
            else if (k < 520) v = U[(size_t)(k - 8) * 2048 + sc];
        } else {
            if (k < 512) v = Wk[((size_t)(layer - 1) * 512 + k) * 2048 + sc];
            else         v = U[((size_t)layer * 512 + (k - 512)) * 2048 + sc];
        }
        outv[i] = f2bf(v);
    }
    *(uint4*)(bp + (size_t)idx * 8) = *(const uint4*)outv;
}

// ---------------------------------------------------------------------------
__global__ void diffk(const float* __restrict__ x, const float* __restrict__ bound,
                      unsigned short* __restrict__ dbuf) {
    int idx = blockIdx.x * 256 + threadIdx.x;
    if (idx >= 255 * 128) return;
    int item = idx & 127, t = idx >> 7;
    const float* xr = x + ((size_t)item * 256 + t) * 6;
    unsigned short row[8];
#pragma unroll
    for (int f = 0; f < 6; f++) row[f] = f2bf((xr[6 + f] - xr[f]) / bound[f]);
    row[6] = 0; row[7] = 0;
    *(uint4*)(dbuf + (size_t)idx * 8) = *(const uint4*)row;
}

// ---------------------------------------------------------------------------
// Persistent LSTM: block -> stage = blk&7 (layer=stage>>1, mg=stage&1), cg=blk>>3
// Flags (padded x32 ints): fastf[fid*32] own fast ("t+1" = step t done, sc0);
// slowf[fid*32] publish ("slot p visible" when >= p, stored at TAIL of step p);
// slowf[fid*32+1] liveness ("t+1" = step t done, stored at TAIL of step t).
// stg slot s holds h of step s-1 (written in body of step s; slot 255 post-loop).
// ---------------------------------------------------------------------------
__global__ __launch_bounds__(256, 1) void lstm_persist(
    const unsigned short* __restrict__ dbuf,
    unsigned short* __restrict__ stg,
    unsigned short* __restrict__ ring,
    const unsigned short* __restrict__ bp_all,
    const float* __restrict__ bias,
    int* __restrict__ slowf,
    int* __restrict__ fastf)
{
    extern __shared__ char smem[];
    float* zsm = (float*)smem;
    unsigned short* wsm = (unsigned short*)(smem + LDS_ZBYTES);

    // ---- entry acquire: purge stale (poison/replay) L1/L2 lines ONCE -----
    (void)__hip_atomic_load(&slowf[0], __ATOMIC_ACQUIRE, __HIP_MEMORY_SCOPE_AGENT);

    const int blk   = blockIdx.x;
    const int stage = blk & 7;
    const int layer = stage >> 1;
    const int mg    = stage & 1;
    const int cg    = blk >> 3;
    const int tid   = threadIdx.x;
    const int w     = tid >> 6;
    const int lane  = tid & 63;
    const int NK16  = (layer == 0) ? NK16_L0 : 64;

    // ---- stage this block's weight tile into LDS (once) ------------------
    {
        const unsigned short* src = bp_all
            + (layer == 0 ? 0ull : (BPE_L0 + (size_t)(layer - 1) * BPE_STR))
            + (size_t)(cg * 2) * NK16 * 64 * 8;
        int nv = 2 * NK16 * 64;
        for (int e = tid; e < nv; e += 256)
            ((uint4*)wsm)[e] = ((const uint4*)src)[e];
    }
    __syncthreads();

    // ---- per-wave constants ----------------------------------------------
    const int mt    = w >> 1;
    const int ntl   = w & 1;
    const int khalf = lane >> 5;
    const int arow  = mg * 64 + mt * 32 + (lane & 31);
    const int aloc  = arow & 63;
    const unsigned short* wbase = wsm + (size_t)ntl * NK16 * 512 + (size_t)lane * 8;
    const int citem = tid >> 2;
    const int jsub  = (tid & 3) << 2;
    const f32x4 bI = *(const f32x4*)(bias + layer * 2048 + cg * 64 + 0  + jsub);
    const f32x4 bF = *(const f32x4*)(bias + layer * 2048 + cg * 64 + 16 + jsub);
    const f32x4 bG = *(const f32x4*)(bias + layer * 2048 + cg * 64 + 32 + jsub);
    const f32x4 bO = *(const f32x4*)(bias + layer * 2048 + cg * 64 + 48 + jsub);

    const int own_base = stage * 32;
    const int lo_base  = (stage - 2) * 32;          // lower layer, same mg
    const int myfp     = (own_base + cg) * 32;
    const int pf       = lane & 31;
    const int ownfp    = (own_base + pf) * 32;
    const int lofp     = (lo_base + pf) * 32;

    unsigned short* ringW = ring + (size_t)layer * RING_L + (size_t)mg * RING_MG;
    const unsigned short* ringR = ringW;

    f32x4 creg = (f32x4){0.f, 0.f, 0.f, 0.f};
    u32x4 A0[16], A1[16];
    unsigned long long hpack_prev = 0ull;
    bool wpre = false;

    int vlow = 0x7fffffff;
    if (layer > 0 && lane < 32) { ld_slow_async(vlow, &slowf[lofp]); }
    VMWAIT(0);

    for (int t = 0; t < 255; t++) {
        f32x16 c0 = {0.f,0.f,0.f,0.f,0.f,0.f,0.f,0.f,0.f,0.f,0.f,0.f,0.f,0.f,0.f,0.f};
        f32x16 c1 = c0, c2 = c0, c3 = c0;

        auto consume = [&](u32x4 (&buf)[16], int wc0) {
#pragma unroll
            for (int j = 0; j < 16; j++) {
                int ch = wc0 + j;
                bf16x8 av = __builtin_bit_cast(bf16x8, buf[j]);
                bf16x8 bv = *(const bf16x8*)(wbase + (size_t)ch * 512);
                f32x16& cc = ((ch & 3) == 0) ? c0 : ((ch & 3) == 1) ? c1
                           : ((ch & 3) == 2) ? c2 : c3;
                cc = __builtin_amdgcn_mfma_f32_32x32x16_bf16(av, bv, cc, 0, 0, 0);
            }
        };

        auto own_poll = [&]() {     // fast L2 path; internal vmcnt(0) drains
            for (;;) {              // W/vlow issued at the prior tail
                int v = (lane < 32) ? ld_fast(&fastf[ownfp]) : 0x7fffffff;
                if (__all(v >= t)) break;
                if (lane < 32) { int v2 = ld_slow(&slowf[ownfp + 1]); v = v > v2 ? v : v2; }
                if (__all(v >= t)) break;
                __builtin_amdgcn_s_sleep(1);
            }
            __builtin_amdgcn_sched_barrier(0);
        };

        const unsigned short* rU = ringR + (size_t)(t & 7) * RING_SLOT
                                 + (size_t)aloc * 16 + (size_t)khalf * 8;
        // in-body cross store target: slot t holds h of step t-1
        unsigned short* crossp = stg + (size_t)t * STG_SLOT
            + (size_t)layer * STG_L + (size_t)mg * STG_MG
            + (size_t)cg * STG_CG + (size_t)citem * 16 + jsub;

        if (layer == 0) {
            own_poll();
            const unsigned short* pD = dbuf + ((size_t)t * 128 + arow) * 8;
            auto issue0 = [&](u32x4 (&buf)[16], int kc0) {
#pragma unroll
                for (int j = 0; j < 16; j++) {
                    int kc = kc0 + j;
                    if (kc == 0 && khalf == 0) { gld16(buf[j], pD); }
                    else {
                        int hk = (kc * 16 + khalf * 8 - 8) & 511;
                        gld16_sc0(buf[j], ringR + (size_t)(t & 7) * RING_SLOT
                                  + (size_t)(hk >> 4) * STG_CG + (size_t)aloc * 16 + (hk & 15));
                    }
                }
            };
            u32x4 ax;
            issue0(A0, 0); issue0(A1, 16);
            {   int hk = (32 * 16 + khalf * 8 - 8) & 511;
                gld16_sc0(ax, ringR + (size_t)(t & 7) * RING_SLOT
                          + (size_t)(hk >> 4) * STG_CG + (size_t)aloc * 16 + (hk & 15)); }
            st_cross8(crossp, hpack_prev);           // newest op [34 outstanding]
            VMWAIT(18); consume(A0, 0);              // A0 retired
            VMWAIT(2);  consume(A1, 16);             // A1 retired (ax,cross remain)
            VMWAIT(1);                               // ax retired (cross remains)
            {   bf16x8 av = __builtin_bit_cast(bf16x8, ax);
                bf16x8 bv = *(const bf16x8*)(wbase + (size_t)32 * 512);
                c0 = __builtin_amdgcn_mfma_f32_32x32x16_bf16(av, bv, c0, 0, 0, 0); }
        } else {
            // ---- in-body W fallback (startup / lower not far enough) -----
            if (!wpre) {
                VMWAIT(0);
                for (;;) {
                    int v = (lane < 32) ? vlow : 0x7fffffff;
                    if (__all(v >= t + 1)) break;
                    __builtin_amdgcn_s_sleep(1);
                    if (lane < 32) ld_slow_async(vlow, &slowf[lofp]);
                    VMWAIT(0);
                }
                __builtin_amdgcn_sched_barrier(0);
                const unsigned short* aW = stg + (size_t)(t + 1) * STG_SLOT
                    + (size_t)(layer - 1) * STG_L + (size_t)mg * STG_MG
                    + (size_t)aloc * 16 + (size_t)khalf * 8;
#pragma unroll
                for (int j = 0; j < 16; j++) gld16(A0[j], aW + (size_t)j * STG_CG);
#pragma unroll
                for (int j = 0; j < 16; j++) gld16(A1[j], aW + (size_t)(16 + j) * STG_CG);
            }
            // ---- own poll: single vmcnt(0) drains W + vlow ---------------
            own_poll();
            consume(A0, 0);                                   // W chunks 0-15
            consume(A1, 16);                                  // W chunks 16-31
            // ---- U phase (ring, XCD-L2) + cross store as newest op -------
#pragma unroll
            for (int j = 0; j < 16; j++) gld16_sc0(A0[j], rU + (size_t)j * STG_CG);
#pragma unroll
            for (int j = 0; j < 16; j++) gld16_sc0(A1[j], rU + (size_t)(16 + j) * STG_CG);
            st_cross8(crossp, hpack_prev);           // newest op [33 outstanding]
            VMWAIT(17); consume(A0, 32);             // U0-15 retired
            VMWAIT(1);  consume(A1, 48);             // all U retired (cross remains)
        }

        f32x16 acc = (c0 + c1) + (c2 + c3);

        // ---- z -> LDS exchange ------------------------------------------
        {
            const int col   = ntl * 32 + (lane & 31);
            const int rbase = mt * 32 + 4 * khalf;
#pragma unroll
            for (int r = 0; r < 16; r++) {
                int row = rbase + (r & 3) + 8 * (r >> 2);
                zsm[row * LDS_ZPAD + col] = acc[r];
            }
        }
        if (layer == 0) {
            __syncthreads();
        } else {
            asm volatile("s_waitcnt lgkmcnt(0)" ::: "memory");
            __builtin_amdgcn_s_barrier();
            asm volatile("" ::: "memory");
            __builtin_amdgcn_sched_barrier(0);
        }

        // ---- cell update ------------------------------------------------
        unsigned long long hpack;
        {
            const float* zr = zsm + citem * LDS_ZPAD + jsub;
            f32x4 zi = *(const f32x4*)(zr + 0);
            f32x4 zf = *(const f32x4*)(zr + 16);
            f32x4 zg = *(const f32x4*)(zr + 32);
            f32x4 zo = *(const f32x4*)(zr + 48);
            unsigned short hq[4];
#pragma unroll
            for (int q = 0; q < 4; q++) {
                float i_ = fsig(zi[q] + bI[q]);
                float f_ = fsig(zf[q] + bF[q]);
                float g_ = ftanh(zg[q] + bG[q]);
                float o_ = fsig(zo[q] + bO[q]);
                float cn = f_ * creg[q] + i_ * g_;
                creg[q] = cn;
                hq[q] = f2bf(o_ * ftanh(cn));
            }
            __builtin_memcpy(&hpack, hq, 8);
        }
        hpack_prev = hpack;

        // ---- ring store + tail drain (ring L2 + in-body cross) -----------
        *(unsigned long long*)(ringW + (size_t)((t + 1) & 7) * RING_SLOT
            + (size_t)cg * STG_CG + (size_t)citem * 16 + jsub) = hpack;
        if (layer == 0) {
            __syncthreads();
        } else {
            asm volatile("s_waitcnt vmcnt(0)" ::: "memory");
            __builtin_amdgcn_s_barrier();
            asm volatile("" ::: "memory");
            __builtin_amdgcn_sched_barrier(0);
        }
        // ---- releases: fast flag, liveness(t+1), publish(t) --------------
        if (tid == 0) {
            int nv = t + 1;
            asm volatile("global_store_dword %0, %1, off sc0"
                         :: "v"(&fastf[myfp]), "v"(nv) : "memory");
            __hip_atomic_store(&slowf[myfp + 1], nv, __ATOMIC_RELAXED,
                               __HIP_MEMORY_SCOPE_AGENT);   // liveness
            __hip_atomic_store(&slowf[myfp], t, __ATOMIC_RELAXED,
                               __HIP_MEMORY_SCOPE_AGENT);   // slot t visible
        }

        // ---- opportunistic W prefetch for step t+1 (slot t+2) ------------
        wpre = false;
        if (layer > 0) {
            if (t < 254) {
                int v = (lane < 32) ? vlow : 0x7fffffff;
                if (__all(v >= t + 2)) {
                    const unsigned short* aW2 = stg + (size_t)(t + 2) * STG_SLOT
                        + (size_t)(layer - 1) * STG_L + (size_t)mg * STG_MG
                        + (size_t)aloc * 16 + (size_t)khalf * 8;
#pragma unroll
                    for (int j = 0; j < 16; j++) gld16(A0[j], aW2 + (size_t)j * STG_CG);
#pragma unroll
                    for (int j = 0; j < 16; j++) gld16(A1[j], aW2 + (size_t)(16 + j) * STG_CG);
                    wpre = true;
                }
            }
            if (lane < 32) ld_slow_async(vlow, &slowf[lofp]);  // drained at next poll
        }
    }

    // ---- post-loop: cross-store slot 255 (h of step 254), publish 255 ----
    {
        unsigned short* crossp = stg + 255ull * STG_SLOT
            + (size_t)layer * STG_L + (size_t)mg * STG_MG
            + (size_t)cg * STG_CG + (size_t)citem * 16 + jsub;
        st_cross8(crossp, hpack_prev);
    }
    asm volatile("s_waitcnt vmcnt(0)" ::: "memory");
    __syncthreads();
    if (tid == 0)
        __hip_atomic_store(&slowf[myfp], 255, __ATOMIC_RELAXED,
                           __HIP_MEMORY_SCOPE_AGENT);
}

// ---------------------------------------------------------------------------
__global__ void headk(const unsigned short* __restrict__ stg,
                      const float* __restrict__ Wd, const float* __restrict__ bd,
                      const float* __restrict__ bound, const float* __restrict__ centre,
                      float* __restrict__ out) {
    (void)__hip_atomic_load((const int*)stg, __ATOMIC_ACQUIRE, __HIP_MEMORY_SCOPE_AGENT);
    int idx = blockIdx.x * 256 + threadIdx.x;
    if (idx >= 12288) return;
    int dd = idx % 3;
    int rest = idx / 3;
    int sdx = rest & 31;
    int b = rest >> 5;
    size_t base = (size_t)(224 + sdx) * STG_SLOT + 3ull * STG_L
                + (size_t)(b >> 6) * STG_MG + (size_t)(b & 63) * 16;
    float acc = 0.0f;
    for (int jj = 0; jj < 512; jj++) {
        unsigned short hv = stg[base + (size_t)(jj >> 4) * STG_CG + (jj & 15)];
        acc += bf2f(hv) * Wd[jj * 3 + dd];
    }
    float o = acc + bd[dd];
    out[idx] = o;
    out[12288 + idx] = o * bound[dd] + centre[dd];
}

// ---------------------------------------------------------------------------
extern "C" void kernel_launch(void* const* d_in, const int* in_sizes, int n_in,
                              void* d_out, int out_size, void* d_ws, size_t ws_size,
                              hipStream_t stream) {
    const float* x      = (const float*)d_in[0];
    const float* centre = (const float*)d_in[1];
    const float* bound  = (const float*)d_in[2];
    const float* W0     = (const float*)d_in[3];
    const float* Wk     = (const float*)d_in[4];
    const float* U      = (const float*)d_in[5];
    const float* b      = (const float*)d_in[6];
    const float* Wd     = (const float*)d_in[7];
    const float* bd     = (const float*)d_in[8];

    char* ws = (char*)d_ws;
    unsigned short* stg     = (unsigned short*)(ws + OFF_STG);
    unsigned short* dbuf    = (unsigned short*)(ws + OFF_D);
    float*          bias_ws = (float*)(ws + OFF_BIAS);
    int*            slowf   = (int*)(ws + OFF_FLAG);
    int*            fastf   = (int*)(ws + OFF_FFLAG);
    unsigned short* ring    = (unsigned short*)(ws + OFF_RING);
    unsigned short* bp      = (unsigned short*)(ws + OFF_BP);

    (void)hipMemsetAsync(slowf, 0, SZ_FLAG + SZ_FFLAG + SZ_RING, stream);

    prep_bias<<<32, 256, 0, stream>>>(b, bias_ws);
    prep_bp32<<<528, 256, 0, stream>>>(0, NK16_L0, W0, Wk, U, bp);
    for (int l = 1; l < 4; l++)
        prep_bp32<<<1024, 256, 0, stream>>>(l, 64, W0, Wk, U,
                                            bp + BPE_L0 + (size_t)(l - 1) * BPE_STR);
    diffk<<<128, 256, 0, stream>>>(x, bound, dbuf);

    (void)hipFuncSetAttribute((const void*)lstm_persist,
                              hipFuncAttributeMaxDynamicSharedMemorySize, LDS_TOTAL);
    lstm_persist<<<256, 256, LDS_TOTAL, stream>>>(dbuf, stg, ring, bp, bias_ws,
                                                  slowf, fastf);

    headk<<<48, 256, 0, stream>>>(stg, Wd, bd, bound, centre, (float*)d_out);
}